// Round 2
// baseline (223.291 us; speedup 1.0000x reference)
//
#include <hip/hip_runtime.h>

// DiffNet, fully fused: all 3 layers in ONE kernel, one workgroup per batch row.
// Exact algebraic collapse of the two 1x1 convs (affine in meta, no nonlinearity):
//   Wv = vi @ W.T (pre-bias), vj = relu(Wv + b)
//   A_c = sum_h c2w[h]*c1w[h][c],  D = sum_h c2w[h]*c1b[h] + c2b
//   s1 = sum_i vi, s2 = sum_i vi^2   (per row)
//   delta = scale * (A0*s2 + A1*Wv + (A2*vj + D)*s1),  out = vj + delta
// Rows are independent through ALL layers -> no inter-block communication.

template<int N>
__device__ __forceinline__ void rowsums(const float* __restrict__ v, int lane,
                                        float& s1, float& s2) {
    // All waves compute this redundantly (same addresses -> LDS broadcast).
    const float4* v4 = reinterpret_cast<const float4*>(v);
    float p1 = 0.f, p2 = 0.f;
    #pragma unroll
    for (int q = 0; q < N / 256; ++q) {
        float4 a = v4[q * 64 + lane];
        p1 += (a.x + a.y) + (a.z + a.w);
        p2 += a.x * a.x + a.y * a.y + a.z * a.z + a.w * a.w;
    }
    #pragma unroll
    for (int s = 32; s > 0; s >>= 1) {
        p1 += __shfl_xor(p1, s);
        p2 += __shfl_xor(p2, s);
    }
    s1 = p1; s2 = p2;
}

template<int IIN, int OUT>
__device__ __forceinline__ void layer(const float* __restrict__ W,    // [OUT, IIN]
                                      const float* __restrict__ bias, // [OUT]
                                      const float* __restrict__ vin,  // LDS [IIN]
                                      float* __restrict__ vout,       // LDS [OUT] or null
                                      float* __restrict__ gout,       // global or null
                                      float s1, float s2,
                                      float A0, float A1, float A2, float Dd,
                                      float scale, int lane, int wave) {
    constexpr int CPW = OUT / 16;      // columns per wave (16 waves/block)
    const int col0 = wave * CPW;
    float acc[CPW];
    #pragma unroll
    for (int c = 0; c < CPW; ++c) acc[c] = 0.f;

    const float4* vin4 = reinterpret_cast<const float4*>(vin);
    #pragma unroll
    for (int q = 0; q < IIN / 256; ++q) {
        const float4 v = vin4[q * 64 + lane];          // 1 ds_read_b128, reused CPW times
        #pragma unroll
        for (int c = 0; c < CPW; ++c) {
            const float4 w = *reinterpret_cast<const float4*>(
                W + (size_t)(col0 + c) * IIN + q * 256 + lane * 4);   // coalesced 1KB/wave
            acc[c] = fmaf(w.w, v.w, fmaf(w.z, v.z, fmaf(w.y, v.y, fmaf(w.x, v.x, acc[c]))));
        }
    }

    #pragma unroll
    for (int c = 0; c < CPW; ++c) {
        float t = acc[c];
        #pragma unroll
        for (int s = 32; s > 0; s >>= 1) t += __shfl_xor(t, s);
        const float Wv  = t;                            // every lane holds the total
        const float vj  = fmaxf(Wv + bias[col0 + c], 0.f);
        const float val = vj + scale * (A0 * s2 + A1 * Wv + (A2 * vj + Dd) * s1);
        if (lane == c) {                                // one lane commits col c
            if (vout) vout[col0 + c] = val;
            if (gout) gout[col0 + c] = val;
        }
    }
}

__launch_bounds__(1024, 1)
__global__ void diffnet_fused(const float* __restrict__ x,
                              const float* __restrict__ W1, const float* __restrict__ b1,
                              const float* __restrict__ W2, const float* __restrict__ b2,
                              const float* __restrict__ W3, const float* __restrict__ b3,
                              const float* __restrict__ c1w, const float* __restrict__ c1b,
                              const float* __restrict__ c2w, const float* __restrict__ c2b,
                              const int* __restrict__ bn, float* __restrict__ out)
{
    __shared__ float bufA[1024];
    __shared__ float bufB[512];
    const int tid  = threadIdx.x;
    const int lane = tid & 63;
    const int wave = tid >> 6;
    const int row  = blockIdx.x;

    // stage this row of x (coalesced, 1 float/thread)
    bufA[tid] = x[row * 1024 + tid];

    // collapsed conv constants (uniform; scalar loads)
    float A0 = 0.f, A1 = 0.f, A2 = 0.f, Dd = c2b[0];
    #pragma unroll
    for (int h = 0; h < 8; ++h) {
        const float w2 = c2w[h];
        A0 = fmaf(w2, c1w[h * 3 + 0], A0);
        A1 = fmaf(w2, c1w[h * 3 + 1], A1);
        A2 = fmaf(w2, c1w[h * 3 + 2], A2);
        Dd = fmaf(w2, c1b[h], Dd);
    }
    const int raw = bn[0];
    const float bnf = (raw > 0 && raw < 1000000) ? (float)raw : __int_as_float(raw);
    const float scale = 0.1f / bnf;

    __syncthreads();

    float s1, s2;
    rowsums<1024>(bufA, lane, s1, s2);
    layer<1024, 512>(W1, b1, bufA, bufB, nullptr, s1, s2, A0, A1, A2, Dd, scale, lane, wave);
    __syncthreads();

    rowsums<512>(bufB, lane, s1, s2);
    layer<512, 512>(W2, b2, bufB, bufA, nullptr, s1, s2, A0, A1, A2, Dd, scale, lane, wave);
    __syncthreads();

    rowsums<512>(bufA, lane, s1, s2);
    layer<512, 256>(W3, b3, bufA, nullptr, out + row * 256, s1, s2, A0, A1, A2, Dd, scale, lane, wave);
}

extern "C" void kernel_launch(void* const* d_in, const int* in_sizes, int n_in,
                              void* d_out, int out_size, void* d_ws, size_t ws_size,
                              hipStream_t stream) {
    const float* x     = (const float*)d_in[0];
    const float* fc1_w = (const float*)d_in[1];
    const float* fc1_b = (const float*)d_in[2];
    const float* fc2_w = (const float*)d_in[3];
    const float* fc2_b = (const float*)d_in[4];
    const float* fc3_w = (const float*)d_in[5];
    const float* fc3_b = (const float*)d_in[6];
    const float* c1w   = (const float*)d_in[7];
    const float* c1b   = (const float*)d_in[8];
    const float* c2w   = (const float*)d_in[9];
    const float* c2b   = (const float*)d_in[10];
    const int*   bn    = (const int*)d_in[11];

    diffnet_fused<<<dim3(32), dim3(1024), 0, stream>>>(
        x, fc1_w, fc1_b, fc2_w, fc2_b, fc3_w, fc3_b,
        c1w, c1b, c2w, c2b, bn, (float*)d_out);
}

// Round 3
// 152.080 us; speedup vs baseline: 1.4682x; 1.4682x over previous
//
#include <hip/hip_runtime.h>
#include <hip/hip_cooperative_groups.h>

namespace cg = cooperative_groups;

// DiffNet, cooperative single-dispatch: 3 phases (layers) with grid.sync().
// Exact algebraic collapse of the two 1x1 convs (affine in meta):
//   Wv = vi @ W.T (pre-bias), vj = relu(Wv + b)
//   A_c = sum_h c2w[h]*c1w[h][c],  D = sum_h c2w[h]*c1b[h] + c2b
//   s1 = sum_i vi, s2 = sum_i vi^2   (per row)
//   delta = scale*(A0*s2 + A1*Wv + (A2*vj + D)*s1),  out = vj + delta
// Parallelization per phase: block = (4 output cols) x (ROWS batch rows);
// wave owns one column, accumulates ROWS dots from LDS-staged input rows.
// Weights are read ~(32/ROWS)x total per phase (not 32x as in the R2 attempt).

template<int IIN, int OUT, int ROWS>
__device__ __forceinline__ void phase(const float* __restrict__ vin,   // [32, IIN]
                                      const float* __restrict__ W,     // [OUT, IIN]
                                      const float* __restrict__ bias,  // [OUT]
                                      float* __restrict__ vout,        // [32, OUT]
                                      float* __restrict__ lds,
                                      float* __restrict__ s1s,
                                      float* __restrict__ s2s,
                                      int bid, int lane, int wave,
                                      float A0, float A1, float A2,
                                      float Dd, float scale)
{
    constexpr int CBLK = OUT / 4;      // column-blocks (4 cols per block, 1 per wave)
    constexpr int RBLK = 32 / ROWS;    // row-blocks
    const int colblk = bid % CBLK;
    const int rowblk = bid / CBLK;
    if (rowblk >= RBLK) return;        // (all phases sized so no block is idle)
    const int row0 = rowblk * ROWS;
    const int col  = colblk * 4 + wave;

    // ---- stage ROWS x IIN input rows into LDS (coalesced float4) ----
    {
        const float4* src = reinterpret_cast<const float4*>(vin + (size_t)row0 * IIN);
        float4* dst = reinterpret_cast<float4*>(lds);
        constexpr int N4 = ROWS * IIN / 4;
        #pragma unroll
        for (int k = 0; k < N4 / 256; ++k)
            dst[k * 256 + threadIdx.x] = src[k * 256 + threadIdx.x];
    }
    __syncthreads();

    // ---- per-row s1, s2 (wave-parallel) ----
    constexpr int RPW = ROWS / 4;
    #pragma unroll
    for (int r = 0; r < RPW; ++r) {
        const int b = wave * RPW + r;
        const float4* v4 = reinterpret_cast<const float4*>(lds + b * IIN);
        float p1 = 0.f, p2 = 0.f;
        #pragma unroll
        for (int q = 0; q < IIN / 256; ++q) {
            const float4 a = v4[q * 64 + lane];
            p1 += (a.x + a.y) + (a.z + a.w);
            p2 += a.x * a.x + a.y * a.y + a.z * a.z + a.w * a.w;
        }
        #pragma unroll
        for (int s = 32; s > 0; s >>= 1) {
            p1 += __shfl_xor(p1, s);
            p2 += __shfl_xor(p2, s);
        }
        if (lane == 0) { s1s[b] = p1; s2s[b] = p2; }
    }
    __syncthreads();

    // ---- dot products: wave's column vs ROWS staged rows ----
    float acc[ROWS];
    #pragma unroll
    for (int r = 0; r < ROWS; ++r) acc[r] = 0.f;

    const float4* Wrow = reinterpret_cast<const float4*>(W + (size_t)col * IIN);
    #pragma unroll
    for (int q = 0; q < IIN / 256; ++q) {
        const float4 w4 = Wrow[q * 64 + lane];   // coalesced 1KB/wave
        #pragma unroll
        for (int r = 0; r < ROWS; ++r) {
            const float4 v4 = *reinterpret_cast<const float4*>(
                lds + r * IIN + (q * 64 + lane) * 4);
            acc[r] = fmaf(w4.w, v4.w, fmaf(w4.z, v4.z,
                     fmaf(w4.y, v4.y, fmaf(w4.x, v4.x, acc[r]))));
        }
    }

    // ---- reduce; lane r keeps row r's total ----
    float Wv = 0.f;
    #pragma unroll
    for (int r = 0; r < ROWS; ++r) {
        float t = acc[r];
        #pragma unroll
        for (int s = 32; s > 0; s >>= 1) t += __shfl_xor(t, s);
        if (lane == r) Wv = t;
    }

    // ---- epilogue: lanes 0..ROWS-1 write their row for this column ----
    if (lane < ROWS) {
        const float vj  = fmaxf(Wv + bias[col], 0.f);
        const float val = vj + scale * (A0 * s2s[lane] + A1 * Wv
                                        + (A2 * vj + Dd) * s1s[lane]);
        vout[(size_t)(row0 + lane) * OUT + col] = val;
    }
}

__global__ void __launch_bounds__(256, 1)
diffnet_coop(const float* __restrict__ x,
             const float* __restrict__ W1, const float* __restrict__ b1,
             const float* __restrict__ W2, const float* __restrict__ b2,
             const float* __restrict__ W3, const float* __restrict__ b3,
             const float* __restrict__ c1w, const float* __restrict__ c1b,
             const float* __restrict__ c2w, const float* __restrict__ c2b,
             const int* __restrict__ bn,
             float* __restrict__ t1, float* __restrict__ t2,
             float* __restrict__ out)
{
    __shared__ float lds[16 * 1024];
    __shared__ float s1s[16], s2s[16];

    const int bid  = blockIdx.x;
    const int lane = threadIdx.x & 63;
    const int wave = threadIdx.x >> 6;

    // collapsed conv constants (uniform scalar loads)
    float A0 = 0.f, A1 = 0.f, A2 = 0.f, Dd = c2b[0];
    #pragma unroll
    for (int h = 0; h < 8; ++h) {
        const float w2 = c2w[h];
        A0 = fmaf(w2, c1w[h * 3 + 0], A0);
        A1 = fmaf(w2, c1w[h * 3 + 1], A1);
        A2 = fmaf(w2, c1w[h * 3 + 2], A2);
        Dd = fmaf(w2, c1b[h], Dd);
    }
    const int raw = bn[0];
    const float bnf = (raw > 0 && raw < 1000000) ? (float)raw : __int_as_float(raw);
    const float scale = 0.1f / bnf;

    cg::grid_group grid = cg::this_grid();

    // phase 1: x[32,1024] -> t1[32,512]   (256 blocks: 128 colblk x 2 rowblk)
    phase<1024, 512, 16>(x, W1, b1, t1, lds, s1s, s2s, bid, lane, wave,
                         A0, A1, A2, Dd, scale);
    __threadfence();
    grid.sync();

    // phase 2: t1 -> t2[32,512]           (256 blocks: 128 x 2)
    phase<512, 512, 16>(t1, W2, b2, t2, lds, s1s, s2s, bid, lane, wave,
                        A0, A1, A2, Dd, scale);
    __threadfence();
    grid.sync();

    // phase 3: t2 -> out[32,256]          (256 blocks: 64 colblk x 4 rowblk, ROWS=8)
    phase<512, 256, 8>(t2, W3, b3, out, lds, s1s, s2s, bid, lane, wave,
                       A0, A1, A2, Dd, scale);
}

extern "C" void kernel_launch(void* const* d_in, const int* in_sizes, int n_in,
                              void* d_out, int out_size, void* d_ws, size_t ws_size,
                              hipStream_t stream) {
    const float* x     = (const float*)d_in[0];
    const float* fc1_w = (const float*)d_in[1];
    const float* fc1_b = (const float*)d_in[2];
    const float* fc2_w = (const float*)d_in[3];
    const float* fc2_b = (const float*)d_in[4];
    const float* fc3_w = (const float*)d_in[5];
    const float* fc3_b = (const float*)d_in[6];
    const float* c1w   = (const float*)d_in[7];
    const float* c1b   = (const float*)d_in[8];
    const float* c2w   = (const float*)d_in[9];
    const float* c2b   = (const float*)d_in[10];
    const int*   bn    = (const int*)d_in[11];

    float* t1  = (float*)d_ws;          // [32, 512]
    float* t2  = t1 + 32 * 512;         // [32, 512]
    float* out = (float*)d_out;         // [32, 256]

    void* args[] = { (void*)&x,
                     (void*)&fc1_w, (void*)&fc1_b,
                     (void*)&fc2_w, (void*)&fc2_b,
                     (void*)&fc3_w, (void*)&fc3_b,
                     (void*)&c1w, (void*)&c1b, (void*)&c2w, (void*)&c2b,
                     (void*)&bn, (void*)&t1, (void*)&t2, (void*)&out };

    hipLaunchCooperativeKernel((const void*)diffnet_coop,
                               dim3(256), dim3(256), args, 0, stream);
}

// Round 4
// 75.864 us; speedup vs baseline: 2.9433x; 2.0047x over previous
//
#include <hip/hip_runtime.h>

// DiffNet, single-dispatch with hand-rolled grid barrier (cg::grid.sync measured
// ~55us/sync on this stack -- replaced with arrive-and-spin atomics).
// Exact algebraic collapse of the two 1x1 convs (affine in meta):
//   Wv = vi @ W.T (pre-bias), vj = relu(Wv + b)
//   A_c = sum_h c2w[h]*c1w[h][c],  D = sum_h c2w[h]*c1b[h] + c2b
//   s1 = sum_i vi, s2 = sum_i vi^2   (per row)
//   delta = scale*(A0*s2 + A1*Wv + (A2*vj + D)*s1),  out = vj + delta
// Barrier counters live in d_ws and are zeroed by a leading hipMemsetAsync node
// on every kernel_launch -> deterministic across graph replays.

#define NBLK 256u

__device__ __forceinline__ void gridbar(unsigned int* cnt) {
    __syncthreads();
    if (threadIdx.x == 0) {
        __threadfence();  // release: make this block's global writes visible
        __hip_atomic_fetch_add(cnt, 1u, __ATOMIC_ACQ_REL, __HIP_MEMORY_SCOPE_AGENT);
        while (__hip_atomic_load(cnt, __ATOMIC_ACQUIRE, __HIP_MEMORY_SCOPE_AGENT) < NBLK) { }
        __threadfence();  // acquire: invalidate stale cached lines before reading
    }
    __syncthreads();
}

template<int IIN, int OUT, int ROWS>
__device__ __forceinline__ void phase(const float* __restrict__ vin,   // [32, IIN]
                                      const float* __restrict__ W,     // [OUT, IIN]
                                      const float* __restrict__ bias,  // [OUT]
                                      float* __restrict__ vout,        // [32, OUT]
                                      float* __restrict__ lds,
                                      float* __restrict__ s1s,
                                      float* __restrict__ s2s,
                                      int bid, int lane, int wave,
                                      float A0, float A1, float A2,
                                      float Dd, float scale)
{
    constexpr int CBLK = OUT / 4;      // column-blocks (4 cols per block, 1 per wave)
    constexpr int RBLK = 32 / ROWS;    // row-blocks
    const int colblk = bid % CBLK;
    const int rowblk = bid / CBLK;
    if (rowblk >= RBLK) return;        // (all phases sized so no block is idle)
    const int row0 = rowblk * ROWS;
    const int col  = colblk * 4 + wave;

    // ---- stage ROWS x IIN input rows into LDS (coalesced float4) ----
    {
        const float4* src = reinterpret_cast<const float4*>(vin + (size_t)row0 * IIN);
        float4* dst = reinterpret_cast<float4*>(lds);
        constexpr int N4 = ROWS * IIN / 4;
        #pragma unroll
        for (int k = 0; k < N4 / 256; ++k)
            dst[k * 256 + threadIdx.x] = src[k * 256 + threadIdx.x];
    }
    __syncthreads();

    // ---- per-row s1, s2 (wave-parallel) ----
    constexpr int RPW = ROWS / 4;
    #pragma unroll
    for (int r = 0; r < RPW; ++r) {
        const int b = wave * RPW + r;
        const float4* v4 = reinterpret_cast<const float4*>(lds + b * IIN);
        float p1 = 0.f, p2 = 0.f;
        #pragma unroll
        for (int q = 0; q < IIN / 256; ++q) {
            const float4 a = v4[q * 64 + lane];
            p1 += (a.x + a.y) + (a.z + a.w);
            p2 += a.x * a.x + a.y * a.y + a.z * a.z + a.w * a.w;
        }
        #pragma unroll
        for (int s = 32; s > 0; s >>= 1) {
            p1 += __shfl_xor(p1, s);
            p2 += __shfl_xor(p2, s);
        }
        if (lane == 0) { s1s[b] = p1; s2s[b] = p2; }
    }
    __syncthreads();

    // ---- dot products: wave's column vs ROWS staged rows ----
    float acc[ROWS];
    #pragma unroll
    for (int r = 0; r < ROWS; ++r) acc[r] = 0.f;

    const float4* Wrow = reinterpret_cast<const float4*>(W + (size_t)col * IIN);
    #pragma unroll
    for (int q = 0; q < IIN / 256; ++q) {
        const float4 w4 = Wrow[q * 64 + lane];   // coalesced 1KB/wave
        #pragma unroll
        for (int r = 0; r < ROWS; ++r) {
            const float4 v4 = *reinterpret_cast<const float4*>(
                lds + r * IIN + (q * 64 + lane) * 4);
            acc[r] = fmaf(w4.w, v4.w, fmaf(w4.z, v4.z,
                     fmaf(w4.y, v4.y, fmaf(w4.x, v4.x, acc[r]))));
        }
    }

    // ---- reduce; lane r keeps row r's total ----
    float Wv = 0.f;
    #pragma unroll
    for (int r = 0; r < ROWS; ++r) {
        float t = acc[r];
        #pragma unroll
        for (int s = 32; s > 0; s >>= 1) t += __shfl_xor(t, s);
        if (lane == r) Wv = t;
    }

    // ---- epilogue: lanes 0..ROWS-1 write their row for this column ----
    if (lane < ROWS) {
        const float vj  = fmaxf(Wv + bias[col], 0.f);
        const float val = vj + scale * (A0 * s2s[lane] + A1 * Wv
                                        + (A2 * vj + Dd) * s1s[lane]);
        vout[(size_t)(row0 + lane) * OUT + col] = val;
    }
}

__global__ void __launch_bounds__(256, 1)
diffnet_onekernel(const float* __restrict__ x,
                  const float* __restrict__ W1, const float* __restrict__ b1,
                  const float* __restrict__ W2, const float* __restrict__ b2,
                  const float* __restrict__ W3, const float* __restrict__ b3,
                  const float* __restrict__ c1w, const float* __restrict__ c1b,
                  const float* __restrict__ c2w, const float* __restrict__ c2b,
                  const int* __restrict__ bn,
                  float* __restrict__ t1, float* __restrict__ t2,
                  unsigned int* __restrict__ bar,
                  float* __restrict__ out)
{
    __shared__ float lds[16 * 1024];
    __shared__ float s1s[16], s2s[16];

    const int bid  = blockIdx.x;
    const int lane = threadIdx.x & 63;
    const int wave = threadIdx.x >> 6;

    // collapsed conv constants (uniform scalar loads)
    float A0 = 0.f, A1 = 0.f, A2 = 0.f, Dd = c2b[0];
    #pragma unroll
    for (int h = 0; h < 8; ++h) {
        const float w2 = c2w[h];
        A0 = fmaf(w2, c1w[h * 3 + 0], A0);
        A1 = fmaf(w2, c1w[h * 3 + 1], A1);
        A2 = fmaf(w2, c1w[h * 3 + 2], A2);
        Dd = fmaf(w2, c1b[h], Dd);
    }
    const int raw = bn[0];
    const float bnf = (raw > 0 && raw < 1000000) ? (float)raw : __int_as_float(raw);
    const float scale = 0.1f / bnf;

    // phase 1: x[32,1024] -> t1[32,512]   (256 blocks: 128 colblk x 2 rowblk)
    phase<1024, 512, 16>(x, W1, b1, t1, lds, s1s, s2s, bid, lane, wave,
                         A0, A1, A2, Dd, scale);
    gridbar(&bar[0]);

    // phase 2: t1 -> t2[32,512]           (256 blocks: 128 x 2)
    phase<512, 512, 16>(t1, W2, b2, t2, lds, s1s, s2s, bid, lane, wave,
                        A0, A1, A2, Dd, scale);
    gridbar(&bar[1]);

    // phase 3: t2 -> out[32,256]          (256 blocks: 64 colblk x 4 rowblk, ROWS=8)
    phase<512, 256, 8>(t2, W3, b3, out, lds, s1s, s2s, bid, lane, wave,
                       A0, A1, A2, Dd, scale);
}

extern "C" void kernel_launch(void* const* d_in, const int* in_sizes, int n_in,
                              void* d_out, int out_size, void* d_ws, size_t ws_size,
                              hipStream_t stream) {
    const float* x     = (const float*)d_in[0];
    const float* fc1_w = (const float*)d_in[1];
    const float* fc1_b = (const float*)d_in[2];
    const float* fc2_w = (const float*)d_in[3];
    const float* fc2_b = (const float*)d_in[4];
    const float* fc3_w = (const float*)d_in[5];
    const float* fc3_b = (const float*)d_in[6];
    const float* c1w   = (const float*)d_in[7];
    const float* c1b   = (const float*)d_in[8];
    const float* c2w   = (const float*)d_in[9];
    const float* c2b   = (const float*)d_in[10];
    const int*   bn    = (const int*)d_in[11];

    float* t1  = (float*)d_ws;                         // [32, 512]
    float* t2  = t1 + 32 * 512;                        // [32, 512]
    unsigned int* bar = (unsigned int*)((char*)d_ws + 32 * 512 * 2 * sizeof(float));
    float* out = (float*)d_out;                        // [32, 256]

    // zero the two barrier counters every call (graph-capturable, deterministic)
    hipMemsetAsync((void*)bar, 0, 2 * sizeof(unsigned int), stream);

    diffnet_onekernel<<<dim3(NBLK), dim3(256), 0, stream>>>(
        x, fc1_w, fc1_b, fc2_w, fc2_b, fc3_w, fc3_b,
        c1w, c1b, c2w, c2b, bn, t1, t2, bar, out);
}

// Round 5
// 50.180 us; speedup vs baseline: 4.4498x; 1.5118x over previous
//
#include <hip/hip_runtime.h>

// DiffNet, single dispatch, 3 phases, hand-rolled hierarchical grid barrier.
// Math (exact collapse of the two 1x1 convs -- affine in meta):
//   Wv = vi @ W.T (pre-bias), vj = relu(Wv + b)
//   A_c = sum_h c2w[h]*c1w[h][c],  D = sum_h c2w[h]*c1b[h] + c2b
//   s1 = sum_i vi, s2 = sum_i vi^2 (per row)
//   delta = scale*(A0*s2 + A1*Wv + (A2*vj + D)*s1),  out = vj + delta
// Barrier: 32 group counters (128B stride) -> global counter -> release flag;
// spinners use relaxed loads + s_sleep backoff; one acquire fence at exit.
// Next-phase weights are prefetched into registers BEFORE the barrier.

#define NBLK 256

// barrier region layout (uints): per barrier: grp[32] @ stride 32, then
// global counter @ 1024, flag @ 1056; barrier b at base + b*1088.
#define BAR_UINTS 1088

__device__ __forceinline__ void gridbar(unsigned int* base, int bid) {
    __syncthreads();
    if (threadIdx.x == 0) {
        __threadfence();   // release: publish this block's global writes
        const int g = bid >> 3;   // 32 groups of 8 blocks
        unsigned p = __hip_atomic_fetch_add(&base[g * 32], 1u,
                          __ATOMIC_ACQ_REL, __HIP_MEMORY_SCOPE_AGENT);
        if (p == 7u) {
            unsigned q = __hip_atomic_fetch_add(&base[1024], 1u,
                              __ATOMIC_ACQ_REL, __HIP_MEMORY_SCOPE_AGENT);
            if (q == 31u)
                __hip_atomic_store(&base[1056], 1u,
                                   __ATOMIC_RELEASE, __HIP_MEMORY_SCOPE_AGENT);
        }
        while (!__hip_atomic_load(&base[1056],
                                  __ATOMIC_RELAXED, __HIP_MEMORY_SCOPE_AGENT))
            __builtin_amdgcn_s_sleep(8);   // ~500 cycle backoff
        __threadfence();   // acquire: drop stale cached lines
    }
    __syncthreads();
}

#define KEEP4(v) asm volatile("" :: "v"((v).x), "v"((v).y), "v"((v).z), "v"((v).w))
#define KEEP1(v) asm volatile("" :: "v"(v))

template<int IIN, int OUT, int ROWS>
__device__ __forceinline__ void phase(const float* __restrict__ vin,   // [32, IIN]
                                      const float4* __restrict__ wreg, // IIN/256 prefetched
                                      float biasc,                     // bias[col] prefetched
                                      float* __restrict__ vout,        // [32, OUT]
                                      float* __restrict__ lds,
                                      float* __restrict__ s1s,
                                      float* __restrict__ s2s,
                                      int bid, int lane, int wave,
                                      float A0, float A1, float A2,
                                      float Dd, float scale)
{
    constexpr int CBLK = OUT / 4;          // 4 cols/block, 1 per wave
    const int row0 = (bid / CBLK) * ROWS;
    const int col  = (bid % CBLK) * 4 + wave;

    // ---- stage ROWS x IIN rows into LDS (coalesced float4) ----
    {
        const float4* src = reinterpret_cast<const float4*>(vin + (size_t)row0 * IIN);
        float4* dst = reinterpret_cast<float4*>(lds);
        constexpr int N4 = ROWS * IIN / 4;
        #pragma unroll
        for (int k = 0; k < N4 / 256; ++k)
            dst[k * 256 + threadIdx.x] = src[k * 256 + threadIdx.x];
    }
    __syncthreads();

    // ---- per-row s1, s2 (wave-parallel) ----
    constexpr int RPW = ROWS / 4;
    #pragma unroll
    for (int r = 0; r < RPW; ++r) {
        const int b = wave * RPW + r;
        const float4* v4 = reinterpret_cast<const float4*>(lds + b * IIN);
        float p1 = 0.f, p2 = 0.f;
        #pragma unroll
        for (int q = 0; q < IIN / 256; ++q) {
            const float4 a = v4[q * 64 + lane];
            p1 += (a.x + a.y) + (a.z + a.w);
            p2 += a.x * a.x + a.y * a.y + a.z * a.z + a.w * a.w;
        }
        #pragma unroll
        for (int s = 32; s > 0; s >>= 1) {
            p1 += __shfl_xor(p1, s);
            p2 += __shfl_xor(p2, s);
        }
        if (lane == 0) { s1s[b] = p1; s2s[b] = p2; }
    }

    // ---- dot products: wave's column (prefetched W) vs ROWS staged rows ----
    float acc[ROWS];
    #pragma unroll
    for (int r = 0; r < ROWS; ++r) acc[r] = 0.f;

    #pragma unroll
    for (int q = 0; q < IIN / 256; ++q) {
        const float4 w4 = wreg[q];
        #pragma unroll
        for (int r = 0; r < ROWS; ++r) {
            const float4 v4 = *reinterpret_cast<const float4*>(
                lds + r * IIN + (q * 64 + lane) * 4);
            acc[r] = fmaf(w4.w, v4.w, fmaf(w4.z, v4.z,
                     fmaf(w4.y, v4.y, fmaf(w4.x, v4.x, acc[r]))));
        }
    }

    // ---- reduce; lane r keeps row r's total ----
    float Wv = 0.f;
    #pragma unroll
    for (int r = 0; r < ROWS; ++r) {
        float t = acc[r];
        #pragma unroll
        for (int s = 32; s > 0; s >>= 1) t += __shfl_xor(t, s);
        if (lane == r) Wv = t;
    }

    __syncthreads();   // s1s/s2s written by all waves before epilogue reads

    // ---- epilogue: lanes 0..ROWS-1 write their row for this column ----
    if (lane < ROWS) {
        const float vj  = fmaxf(Wv + biasc, 0.f);
        const float val = vj + scale * (A0 * s2s[lane] + A1 * Wv
                                        + (A2 * vj + Dd) * s1s[lane]);
        vout[(size_t)(row0 + lane) * OUT + col] = val;
    }
}

__global__ void __launch_bounds__(256, 1)
diffnet_onekernel(const float* __restrict__ x,
                  const float* __restrict__ W1, const float* __restrict__ b1,
                  const float* __restrict__ W2, const float* __restrict__ b2,
                  const float* __restrict__ W3, const float* __restrict__ b3,
                  const float* __restrict__ c1w, const float* __restrict__ c1b,
                  const float* __restrict__ c2w, const float* __restrict__ c2b,
                  const int* __restrict__ bn,
                  float* __restrict__ t1, float* __restrict__ t2,
                  unsigned int* __restrict__ bar,
                  float* __restrict__ out)
{
    __shared__ float lds[16 * 1024];
    __shared__ float s1s[16], s2s[16];

    const int bid  = blockIdx.x;
    const int lane = threadIdx.x & 63;
    const int wave = threadIdx.x >> 6;

    // collapsed conv constants (uniform scalar loads)
    float A0 = 0.f, A1 = 0.f, A2 = 0.f, Dd = c2b[0];
    #pragma unroll
    for (int h = 0; h < 8; ++h) {
        const float w2 = c2w[h];
        A0 = fmaf(w2, c1w[h * 3 + 0], A0);
        A1 = fmaf(w2, c1w[h * 3 + 1], A1);
        A2 = fmaf(w2, c1w[h * 3 + 2], A2);
        Dd = fmaf(w2, c1b[h], Dd);
    }
    const int raw = bn[0];
    const float bnf = (raw > 0 && raw < 1000000) ? (float)raw : __int_as_float(raw);
    const float scale = 0.1f / bnf;

    const int col12 = (bid & 127) * 4 + wave;   // phase 1/2 column
    const int col3  = (bid & 63) * 4 + wave;    // phase 3 column

    // ---- prefetch phase-1 weights (overlaps x staging) ----
    float4 w1r[4];
    {
        const float4* Wr = reinterpret_cast<const float4*>(W1 + (size_t)col12 * 1024);
        #pragma unroll
        for (int q = 0; q < 4; ++q) w1r[q] = Wr[q * 64 + lane];
    }
    const float bias1 = b1[col12];

    // phase 1: x[32,1024] -> t1[32,512]   (128 colblk x 2 rowblk)
    phase<1024, 512, 16>(x, w1r, bias1, t1, lds, s1s, s2s, bid, lane, wave,
                         A0, A1, A2, Dd, scale);

    // ---- prefetch phase-2 weights BEFORE the barrier (hide behind spin) ----
    float4 w2r[2];
    {
        const float4* Wr = reinterpret_cast<const float4*>(W2 + (size_t)col12 * 512);
        #pragma unroll
        for (int q = 0; q < 2; ++q) w2r[q] = Wr[q * 64 + lane];
    }
    const float bias2 = b2[col12];
    KEEP4(w2r[0]); KEEP4(w2r[1]); KEEP1(bias2);

    gridbar(bar, bid);

    // phase 2: t1 -> t2[32,512]
    phase<512, 512, 16>(t1, w2r, bias2, t2, lds, s1s, s2s, bid, lane, wave,
                        A0, A1, A2, Dd, scale);

    // ---- prefetch phase-3 weights BEFORE the barrier ----
    float4 w3r[2];
    {
        const float4* Wr = reinterpret_cast<const float4*>(W3 + (size_t)col3 * 512);
        #pragma unroll
        for (int q = 0; q < 2; ++q) w3r[q] = Wr[q * 64 + lane];
    }
    const float bias3 = b3[col3];
    KEEP4(w3r[0]); KEEP4(w3r[1]); KEEP1(bias3);

    gridbar(bar + BAR_UINTS, bid);

    // phase 3: t2 -> out[32,256]   (64 colblk x 4 rowblk, ROWS=8)
    phase<512, 256, 8>(t2, w3r, bias3, out, lds, s1s, s2s, bid, lane, wave,
                       A0, A1, A2, Dd, scale);
}

extern "C" void kernel_launch(void* const* d_in, const int* in_sizes, int n_in,
                              void* d_out, int out_size, void* d_ws, size_t ws_size,
                              hipStream_t stream) {
    const float* x     = (const float*)d_in[0];
    const float* fc1_w = (const float*)d_in[1];
    const float* fc1_b = (const float*)d_in[2];
    const float* fc2_w = (const float*)d_in[3];
    const float* fc2_b = (const float*)d_in[4];
    const float* fc3_w = (const float*)d_in[5];
    const float* fc3_b = (const float*)d_in[6];
    const float* c1w   = (const float*)d_in[7];
    const float* c1b   = (const float*)d_in[8];
    const float* c2w   = (const float*)d_in[9];
    const float* c2b   = (const float*)d_in[10];
    const int*   bn    = (const int*)d_in[11];

    float* t1  = (float*)d_ws;                         // [32, 512] = 64KB
    float* t2  = t1 + 32 * 512;                        // [32, 512] = 64KB
    unsigned int* bar = (unsigned int*)(t2 + 32 * 512);
    float* out = (float*)d_out;                        // [32, 256]

    // zero both barriers' counters/flags every call (graph-capturable)
    hipMemsetAsync((void*)bar, 0, 2 * BAR_UINTS * sizeof(unsigned int), stream);

    diffnet_onekernel<<<dim3(NBLK), dim3(256), 0, stream>>>(
        x, fc1_w, fc1_b, fc2_w, fc2_b, fc3_w, fc3_b,
        c1w, c1b, c2w, c2b, bn, t1, t2, bar, out);
}

// Round 6
// 30.354 us; speedup vs baseline: 7.3562x; 1.6532x over previous
//
#include <hip/hip_runtime.h>

// DiffNet, single dispatch, 3 phases, FENCE-FREE grid barrier.
// Math (exact collapse of the two 1x1 convs -- affine in meta):
//   Wv = vi @ W.T (pre-bias), vj = relu(Wv + b)
//   A_c = sum_h c2w[h]*c1w[h][c],  D = sum_h c2w[h]*c1b[h] + c2b
//   s1 = sum_i vi, s2 = sum_i vi^2 (per row)
//   delta = scale*(A0*s2 + A1*Wv + (A2*vj + D)*s1),  out = vj + delta
//
// Key change vs R5: __threadfence() at agent scope on gfx950 must write-back +
// invalidate the non-coherent per-XCD L2s (~10+ us per barrier). Instead,
// inter-phase tensors t1/t2 (64KB each) are exchanged via relaxed AGENT-scope
// 64-bit atomic loads/stores, which route to the coherent point (L3) and need
// no fences. Barrier = s_waitcnt vmcnt(0) + relaxed RMW tree + relaxed poll.
// Weights stay L2-resident since L2 is never invalidated.

#define NBLK 256

// barrier region layout (uints): per barrier: grp[32] @ stride 32 uints,
// global counter @ 1024, flag @ 1056; barrier b at base + b*1088.
#define BAR_UINTS 1088

__device__ __forceinline__ void gridbar(unsigned int* base, int bid) {
    __syncthreads();
    if (threadIdx.x == 0) {
        // all data stores (atomic, L3-bound) were issued by wave 0 -> this
        // wave's vmcnt covers them; no cache fence needed.
        asm volatile("s_waitcnt vmcnt(0)" ::: "memory");
        const int g = bid >> 3;   // 32 groups of 8 blocks
        unsigned p = __hip_atomic_fetch_add(&base[g * 32], 1u,
                          __ATOMIC_RELAXED, __HIP_MEMORY_SCOPE_AGENT);
        if (p == 7u) {
            unsigned q = __hip_atomic_fetch_add(&base[1024], 1u,
                              __ATOMIC_RELAXED, __HIP_MEMORY_SCOPE_AGENT);
            if (q == 31u)
                __hip_atomic_store(&base[1056], 1u,
                                   __ATOMIC_RELAXED, __HIP_MEMORY_SCOPE_AGENT);
        }
        while (!__hip_atomic_load(&base[1056],
                                  __ATOMIC_RELAXED, __HIP_MEMORY_SCOPE_AGENT))
            __builtin_amdgcn_s_sleep(2);
        asm volatile("" ::: "memory");   // compiler barrier only
    }
    __syncthreads();
}

#define KEEP4(v) asm volatile("" :: "v"((v).x), "v"((v).y), "v"((v).z), "v"((v).w))
#define KEEP1(v) asm volatile("" :: "v"(v))

// AIN:  stage input via relaxed agent atomic u64 loads (coherent, L2-bypass)
// AOUT: write output via relaxed agent atomic u64 stores (pairs via LDS regroup)
template<int IIN, int OUT, int ROWS, bool AIN, bool AOUT>
__device__ __forceinline__ void phase(const float* __restrict__ vin,   // [32, IIN]
                                      const float4* __restrict__ wreg, // IIN/256 regs
                                      float biasc,                     // bias[col]
                                      float* __restrict__ vout,        // [32, OUT]
                                      float* __restrict__ lds,
                                      float* __restrict__ s1s,
                                      float* __restrict__ s2s,
                                      float* __restrict__ svals,       // [4*16]
                                      int bid, int lane, int wave,
                                      float A0, float A1, float A2,
                                      float Dd, float scale)
{
    constexpr int CBLK = OUT / 4;          // 4 cols/block, 1 per wave
    const int row0 = (bid / CBLK) * ROWS;
    const int col  = (bid % CBLK) * 4 + wave;

    // ---- stage ROWS x IIN rows into LDS ----
    if (AIN) {
        const unsigned long long* src = reinterpret_cast<const unsigned long long*>(
            vin + (size_t)row0 * IIN);
        float2* dst = reinterpret_cast<float2*>(lds);
        constexpr int N2 = ROWS * IIN / 2;
        #pragma unroll
        for (int k = 0; k < N2 / 256; ++k) {
            unsigned long long u = __hip_atomic_load(
                &src[k * 256 + threadIdx.x], __ATOMIC_RELAXED, __HIP_MEMORY_SCOPE_AGENT);
            float2 f;
            __builtin_memcpy(&f, &u, 8);
            dst[k * 256 + threadIdx.x] = f;
        }
    } else {
        const float4* src = reinterpret_cast<const float4*>(vin + (size_t)row0 * IIN);
        float4* dst = reinterpret_cast<float4*>(lds);
        constexpr int N4 = ROWS * IIN / 4;
        #pragma unroll
        for (int k = 0; k < N4 / 256; ++k)
            dst[k * 256 + threadIdx.x] = src[k * 256 + threadIdx.x];
    }
    __syncthreads();

    // ---- per-row s1, s2 (wave-parallel) ----
    constexpr int RPW = ROWS / 4;
    #pragma unroll
    for (int r = 0; r < RPW; ++r) {
        const int b = wave * RPW + r;
        const float4* v4 = reinterpret_cast<const float4*>(lds + b * IIN);
        float p1 = 0.f, p2 = 0.f;
        #pragma unroll
        for (int q = 0; q < IIN / 256; ++q) {
            const float4 a = v4[q * 64 + lane];
            p1 += (a.x + a.y) + (a.z + a.w);
            p2 += a.x * a.x + a.y * a.y + a.z * a.z + a.w * a.w;
        }
        #pragma unroll
        for (int s = 32; s > 0; s >>= 1) {
            p1 += __shfl_xor(p1, s);
            p2 += __shfl_xor(p2, s);
        }
        if (lane == 0) { s1s[b] = p1; s2s[b] = p2; }
    }

    // ---- dot products: wave's column (prefetched W) vs ROWS staged rows ----
    float acc[ROWS];
    #pragma unroll
    for (int r = 0; r < ROWS; ++r) acc[r] = 0.f;

    #pragma unroll
    for (int q = 0; q < IIN / 256; ++q) {
        const float4 w4 = wreg[q];
        #pragma unroll
        for (int r = 0; r < ROWS; ++r) {
            const float4 v4 = *reinterpret_cast<const float4*>(
                lds + r * IIN + (q * 64 + lane) * 4);
            acc[r] = fmaf(w4.w, v4.w, fmaf(w4.z, v4.z,
                     fmaf(w4.y, v4.y, fmaf(w4.x, v4.x, acc[r]))));
        }
    }

    // ---- reduce; lane r keeps row r's total ----
    float Wv = 0.f;
    #pragma unroll
    for (int r = 0; r < ROWS; ++r) {
        float t = acc[r];
        #pragma unroll
        for (int s = 32; s > 0; s >>= 1) t += __shfl_xor(t, s);
        if (lane == r) Wv = t;
    }

    __syncthreads();   // s1s/s2s complete before epilogue reads

    // ---- epilogue ----
    float val = 0.f;
    if (lane < ROWS) {
        const float vj = fmaxf(Wv + biasc, 0.f);
        val = vj + scale * (A0 * s2s[lane] + A1 * Wv + (A2 * vj + Dd) * s1s[lane]);
    }

    if (AOUT) {
        if (lane < ROWS) svals[wave * 16 + lane] = val;
        __syncthreads();
        // pack col pairs (w,w+1), w in {0,2}; 8-byte aligned since colbase%4==0
        if (threadIdx.x < 2 * ROWS) {
            const int w2 = (threadIdx.x >= ROWS) ? 2 : 0;
            const int r  = threadIdx.x & (ROWS - 1);
            float2 f = make_float2(svals[w2 * 16 + r], svals[(w2 + 1) * 16 + r]);
            unsigned long long u;
            __builtin_memcpy(&u, &f, 8);
            unsigned long long* dst = reinterpret_cast<unsigned long long*>(
                vout + (size_t)(row0 + r) * OUT + (bid % CBLK) * 4 + w2);
            __hip_atomic_store(dst, u, __ATOMIC_RELAXED, __HIP_MEMORY_SCOPE_AGENT);
        }
    } else {
        if (lane < ROWS)
            vout[(size_t)(row0 + lane) * OUT + col] = val;   // final output: plain
    }
}

__global__ void __launch_bounds__(256, 1)
diffnet_onekernel(const float* __restrict__ x,
                  const float* __restrict__ W1, const float* __restrict__ b1,
                  const float* __restrict__ W2, const float* __restrict__ b2,
                  const float* __restrict__ W3, const float* __restrict__ b3,
                  const float* __restrict__ c1w, const float* __restrict__ c1b,
                  const float* __restrict__ c2w, const float* __restrict__ c2b,
                  const int* __restrict__ bn,
                  float* __restrict__ t1, float* __restrict__ t2,
                  unsigned int* __restrict__ bar,
                  float* __restrict__ out)
{
    __shared__ float lds[16 * 1024];
    __shared__ float s1s[16], s2s[16];
    __shared__ float svals[4 * 16];

    const int bid  = blockIdx.x;
    const int lane = threadIdx.x & 63;
    const int wave = threadIdx.x >> 6;

    // collapsed conv constants (uniform scalar loads)
    float A0 = 0.f, A1 = 0.f, A2 = 0.f, Dd = c2b[0];
    #pragma unroll
    for (int h = 0; h < 8; ++h) {
        const float w2 = c2w[h];
        A0 = fmaf(w2, c1w[h * 3 + 0], A0);
        A1 = fmaf(w2, c1w[h * 3 + 1], A1);
        A2 = fmaf(w2, c1w[h * 3 + 2], A2);
        Dd = fmaf(w2, c1b[h], Dd);
    }
    const int raw = bn[0];
    const float bnf = (raw > 0 && raw < 1000000) ? (float)raw : __int_as_float(raw);
    const float scale = 0.1f / bnf;

    const int col12 = (bid & 127) * 4 + wave;   // phase 1/2 column
    const int col3  = (bid & 63) * 4 + wave;    // phase 3 column

    // ---- prefetch phase-1 weights (overlaps x staging) ----
    float4 w1r[4];
    {
        const float4* Wr = reinterpret_cast<const float4*>(W1 + (size_t)col12 * 1024);
        #pragma unroll
        for (int q = 0; q < 4; ++q) w1r[q] = Wr[q * 64 + lane];
    }
    const float bias1 = b1[col12];

    // phase 1: x[32,1024] -> t1[32,512]   (128 colblk x 2 rowblk, atomic out)
    phase<1024, 512, 16, false, true>(x, w1r, bias1, t1, lds, s1s, s2s, svals,
                                      bid, lane, wave, A0, A1, A2, Dd, scale);

    // ---- prefetch phase-2 weights BEFORE the barrier ----
    float4 w2r[2];
    {
        const float4* Wr = reinterpret_cast<const float4*>(W2 + (size_t)col12 * 512);
        #pragma unroll
        for (int q = 0; q < 2; ++q) w2r[q] = Wr[q * 64 + lane];
    }
    const float bias2 = b2[col12];
    KEEP4(w2r[0]); KEEP4(w2r[1]); KEEP1(bias2);

    gridbar(bar, bid);

    // phase 2: t1 -> t2[32,512]   (atomic in, atomic out)
    phase<512, 512, 16, true, true>(t1, w2r, bias2, t2, lds, s1s, s2s, svals,
                                    bid, lane, wave, A0, A1, A2, Dd, scale);

    // ---- prefetch phase-3 weights BEFORE the barrier ----
    float4 w3r[2];
    {
        const float4* Wr = reinterpret_cast<const float4*>(W3 + (size_t)col3 * 512);
        #pragma unroll
        for (int q = 0; q < 2; ++q) w3r[q] = Wr[q * 64 + lane];
    }
    const float bias3 = b3[col3];
    KEEP4(w3r[0]); KEEP4(w3r[1]); KEEP1(bias3);

    gridbar(bar + BAR_UINTS, bid);

    // phase 3: t2 -> out[32,256]   (64 colblk x 4 rowblk, ROWS=8; atomic in, plain out)
    phase<512, 256, 8, true, false>(t2, w3r, bias3, out, lds, s1s, s2s, svals,
                                    bid, lane, wave, A0, A1, A2, Dd, scale);
}

extern "C" void kernel_launch(void* const* d_in, const int* in_sizes, int n_in,
                              void* d_out, int out_size, void* d_ws, size_t ws_size,
                              hipStream_t stream) {
    const float* x     = (const float*)d_in[0];
    const float* fc1_w = (const float*)d_in[1];
    const float* fc1_b = (const float*)d_in[2];
    const float* fc2_w = (const float*)d_in[3];
    const float* fc2_b = (const float*)d_in[4];
    const float* fc3_w = (const float*)d_in[5];
    const float* fc3_b = (const float*)d_in[6];
    const float* c1w   = (const float*)d_in[7];
    const float* c1b   = (const float*)d_in[8];
    const float* c2w   = (const float*)d_in[9];
    const float* c2b   = (const float*)d_in[10];
    const int*   bn    = (const int*)d_in[11];

    float* t1  = (float*)d_ws;                         // [32, 512] = 64KB
    float* t2  = t1 + 32 * 512;                        // [32, 512] = 64KB
    unsigned int* bar = (unsigned int*)(t2 + 32 * 512);
    float* out = (float*)d_out;                        // [32, 256]

    // zero both barriers' counters/flags every call (graph-capturable;
    // memset kernel's dispatch-end release makes zeros visible to L3 atomics)
    hipMemsetAsync((void*)bar, 0, 2 * BAR_UINTS * sizeof(unsigned int), stream);

    diffnet_onekernel<<<dim3(NBLK), dim3(256), 0, stream>>>(
        x, fc1_w, fc1_b, fc2_w, fc2_b, fc3_w, fc3_b,
        c1w, c1b, c2w, c2b, bn, t1, t2, bar, out);
}